// Round 5
// baseline (347.925 us; speedup 1.0000x reference)
//
#include <hip/hip_runtime.h>
#include <hip/hip_bf16.h>

// PLRNN step: out = A*z + relu(z - rowmean(z)) @ W^T + h,  A=diag(AW), W=AW-diag
// Rewritten: out = (z_act @ AW^T) + [A*min(z,mu) + h]   (exact identity)
// Round 8 = round 7 resubmitted (bench died in container acquisition, not in
// the kernel; bounds/LDS/race audit clean). Persistent-block tile pipeline:
// rounds 4-6 lesson: any epilogue global z re-read inflates FETCH+WRITE by
// ~100MB each (cache churn with z*2+out ~ 400MB streaming through 256MB L3);
// corr-in-LDS (sC) is the only clean-traffic design (r3: WRITE == exact out).
// Round 3's 109us was phase-serialized (memory idle during GEMM). Fix: each
// block owns 8 tiles; z loads for tile k+1 are issued BEFORE the K-loop and
// epilogue of tile k (HBM latency hides under GEMM + store stream), then
// phase-1 for k+1 goes into the other half of double-buffered sA/sC. One
// barrier per tile. LDS 130KB -> 1 block/CU (8 waves); overlap comes from
// the pipeline, not TLP.

#define DZV 512
#define BM 32
#define LDA 520   // LDS row stride (shorts): 1040 B, 16B-aligned, non-pow2 bank stride
#define NBLK 256  // persistent blocks, 1 per CU
#define NTILE 8   // (65536/BM)/NBLK = 2048/256

typedef __attribute__((ext_vector_type(8))) short short8;  // 8 bf16 = 4 VGPRs
typedef __attribute__((ext_vector_type(4))) float f32x4;   // MFMA C/D frag

__device__ __forceinline__ unsigned short f2bf(float x) {
  __hip_bfloat16 b = __float2bfloat16(x);
  return __builtin_bit_cast(unsigned short, b);
}
__device__ __forceinline__ float bf2f(unsigned short u) {
  return __builtin_bit_cast(float, (unsigned int)u << 16);
}

// Prep: pack AW (fp32) into bf16 MFMA-B-fragment order + extract diagonal.
// Frag idx=(T*16+s)*64+L holds 8 bf16 = AW[T*16+(L&15)][s*32+(L>>4)*8 + j]:
// a wave's B-frag load (lane L reads idx base+L) is 1KB contiguous, L2-hot.
__global__ void pack_b(const float* __restrict__ AW, unsigned short* __restrict__ AWp,
                       float* __restrict__ Adiag) {
  int idx = blockIdx.x * 256 + threadIdx.x;     // 0..32767
  int L = idx & 63, s = (idx >> 6) & 15, T = idx >> 10;
  int n = T * 16 + (L & 15);
  int k = s * 32 + (L >> 4) * 8;
  const float4* src = (const float4*)(AW + n * DZV + k);
  float4 a = src[0], b = src[1];
  union { unsigned short u[8]; short8 v; } p;
  p.u[0] = f2bf(a.x); p.u[1] = f2bf(a.y); p.u[2] = f2bf(a.z); p.u[3] = f2bf(a.w);
  p.u[4] = f2bf(b.x); p.u[5] = f2bf(b.y); p.u[6] = f2bf(b.z); p.u[7] = f2bf(b.w);
  *(short8*)(AWp + idx * 8) = p.v;
  if (idx < DZV) Adiag[idx] = AW[idx * (DZV + 1)];
}

__global__ __launch_bounds__(512, 2) void plrnn_step(
    const float* __restrict__ z, const float* __restrict__ h,
    const unsigned short* __restrict__ AWp, const float* __restrict__ Adiag,
    float* __restrict__ out)
{
  __shared__ unsigned short sA[2][BM * LDA];  // z_act panels (bf16), 2x33.3 KB
  __shared__ unsigned short sC[2][BM * LDA];  // corr panels (bf16), 2x33.3 KB

  const int t = threadIdx.x;
  const int lane = t & 63;
  const int wave = t >> 6;           // 8 waves cover N=512
  const int lr   = lane & 15;
  const int quad = lane >> 4;
  const int nbase = wave * 64;
  const int rr = t >> 4;             // 0..31, 16 threads per row
  const int c  = t & 15;

  // B frag base pointers (packed global, lane-contiguous 1KB per frag-load)
  const unsigned short* bb[4];
  #pragma unroll
  for (int nt = 0; nt < 4; ++nt)
    bb[nt] = AWp + (((wave * 4 + nt) * 16) * 64 + lane) * 8;

  float4 v[8];   // z row chunk for the NEXT tile, in flight across the K-loop

  // phase-1: consume v -> mean (shuffle reduce), relu->sA[buf], corr->sC[buf]
  auto phase1 = [&](int buf) {
    float s = 0.f;
    #pragma unroll
    for (int i = 0; i < 8; ++i)
      s += (v[i].x + v[i].y) + (v[i].z + v[i].w);
    s += __shfl_xor(s, 1);
    s += __shfl_xor(s, 2);
    s += __shfl_xor(s, 4);
    s += __shfl_xor(s, 8);
    const float mu = s * (1.0f / 512.0f);
    #pragma unroll
    for (int i = 0; i < 8; ++i) {
      const int c4 = c + i * 16;               // float4 column index
      float4 Ad = ((const float4*)Adiag)[c4];  // L1-hot, 2KB shared
      float4 hv = ((const float4*)h)[c4];
      union { unsigned short u[4]; ushort4 v4; } pa, pc;
      pa.u[0] = f2bf(fmaxf(v[i].x - mu, 0.f));
      pa.u[1] = f2bf(fmaxf(v[i].y - mu, 0.f));
      pa.u[2] = f2bf(fmaxf(v[i].z - mu, 0.f));
      pa.u[3] = f2bf(fmaxf(v[i].w - mu, 0.f));
      pc.u[0] = f2bf(Ad.x * fminf(v[i].x, mu) + hv.x);
      pc.u[1] = f2bf(Ad.y * fminf(v[i].y, mu) + hv.y);
      pc.u[2] = f2bf(Ad.z * fminf(v[i].z, mu) + hv.z);
      pc.u[3] = f2bf(Ad.w * fminf(v[i].w, mu) + hv.w);
      *(ushort4*)&sA[buf][rr * LDA + c4 * 4] = pa.v4;
      *(ushort4*)&sC[buf][rr * LDA + c4 * 4] = pc.v4;
    }
  };

  // ---- Prologue: tile 0 -> buf 0 ----
  {
    const float4* zr = (const float4*)(z + ((long)blockIdx.x * BM + rr) * DZV);
    #pragma unroll
    for (int i = 0; i < 8; ++i) v[i] = zr[c + i * 16];   // coalesced 256B runs
  }
  phase1(0);

  short8 bf[2][4];
  #pragma unroll
  for (int nt = 0; nt < 4; ++nt)                 // s=0 prefetch for tile 0
    bf[0][nt] = *(const short8*)(bb[nt]);
  __syncthreads();

  // ---- Persistent tile loop ----
  #pragma unroll 1
  for (int k = 0; k < NTILE; ++k) {
    const int cur = k & 1;
    const int row0 = (blockIdx.x + k * NBLK) * BM;

    // 1. issue z loads for tile k+1 NOW; they fly under the K-loop + stores
    if (k + 1 < NTILE) {
      const float4* zr =
          (const float4*)(z + ((long)(blockIdx.x + (k + 1) * NBLK) * BM + rr) * DZV);
      #pragma unroll
      for (int i = 0; i < 8; ++i) v[i] = zr[c + i * 16];
    }

    // 2. GEMM on buf cur: 2M x 4N frags per wave, B double-buffered in regs
    const unsigned short* abase = &sA[cur][lr * LDA + quad * 8];
    f32x4 acc[2][4];
    #pragma unroll
    for (int mt = 0; mt < 2; ++mt)
      #pragma unroll
      for (int nt = 0; nt < 4; ++nt)
        acc[mt][nt] = (f32x4){0.f, 0.f, 0.f, 0.f};

    #pragma unroll
    for (int s = 0; s < 16; ++s) {   // k-dim = s*32
      const int cs = s & 1, ns = cs ^ 1;
      short8 af0 = *(const short8*)(abase + s * 32);            // ds_read_b128
      short8 af1 = *(const short8*)(abase + 16 * LDA + s * 32);
      if (s < 15) {                  // prefetch B for s+1 (L2, dwordx4)
        #pragma unroll
        for (int nt = 0; nt < 4; ++nt)
          bf[ns][nt] = *(const short8*)(bb[nt] + (s + 1) * 512);
      }
      #pragma unroll
      for (int nt = 0; nt < 4; ++nt) {
        acc[0][nt] = __builtin_amdgcn_mfma_f32_16x16x32_bf16(af0, bf[cs][nt], acc[0][nt], 0, 0, 0);
        acc[1][nt] = __builtin_amdgcn_mfma_f32_16x16x32_bf16(af1, bf[cs][nt], acc[1][nt], 0, 0, 0);
      }
    }

    // 3. epilogue: out = acc + corr (corr from sC[cur], LDS); round-3 store
    //    order: nt innermost -> adjacent 64B segments back-to-back, L2 merges.
    #pragma unroll
    for (int mt = 0; mt < 2; ++mt) {
      #pragma unroll
      for (int r = 0; r < 4; ++r) {
        const int lm = mt * 16 + quad * 4 + r;   // C/D layout: row = quad*4 + reg
        float corr[4];
        #pragma unroll
        for (int nt = 0; nt < 4; ++nt)
          corr[nt] = bf2f(sC[cur][lm * LDA + nbase + nt * 16 + lr]);
        float* orow = out + (long)(row0 + lm) * DZV + nbase + lr;
        #pragma unroll
        for (int nt = 0; nt < 4; ++nt)
          orow[nt * 16] = acc[mt][nt][r] + corr[nt];
      }
    }

    // 4. phase-1 for tile k+1 into the other buffer; re-prefetch B s=0
    if (k + 1 < NTILE) {
      phase1(cur ^ 1);
      #pragma unroll
      for (int nt = 0; nt < 4; ++nt)
        bf[0][nt] = *(const short8*)(bb[nt]);
      __syncthreads();   // one barrier per tile
    }
  }
}

extern "C" void kernel_launch(void* const* d_in, const int* in_sizes, int n_in,
                              void* d_out, int out_size, void* d_ws, size_t ws_size,
                              hipStream_t stream) {
  const float* z  = (const float*)d_in[0];
  const float* AW = (const float*)d_in[1];
  const float* h  = (const float*)d_in[2];
  float* out = (float*)d_out;
  unsigned short* AWp = (unsigned short*)d_ws;                     // 512 KB packed bf16
  float* Adiag = (float*)((char*)d_ws + DZV * DZV * sizeof(unsigned short)); // 2 KB

  pack_b<<<128, 256, 0, stream>>>(AW, AWp, Adiag);
  plrnn_step<<<NBLK, 512, 0, stream>>>(z, h, AWp, Adiag, out);
}

// Round 6
// 262.577 us; speedup vs baseline: 1.3250x; 1.3250x over previous
//
#include <hip/hip_runtime.h>
#include <hip/hip_bf16.h>

// PLRNN step: out = A*z + relu(z - rowmean(z)) @ W^T + h,  A=diag(AW), W=AW-diag
// Rewritten: out = (z_act @ AW^T) + [A*min(z,mu) + h]   (exact identity)
// Round 9 = round-3 kernel (109us, the measured best; clean traffic profile:
// FETCH 73MB / WRITE 131MB) + ONE change: B register pipeline deepened from
// depth-1 to depth-2 (3 buffers, prefetch s+2), with s=0/s=1 B loads issued
// at kernel top so they fly under phase-1's z loads. Theory: K-loop waves
// stall on L2 B-frag latency (~200-400cy) that 8 MFMAs of slack can't cover
// -> MfmaUtil 12%. Structural departures (BM=64, epilogue recompute, NT
// stores, persistent blocks) all regressed in r4-r8; traffic must stay
// byte-identical to r3.

#define DZV 512
#define BM 32
#define LDA 520   // LDS row stride (shorts): 1040 B, 16B-aligned, non-pow2 bank stride

typedef __attribute__((ext_vector_type(8))) short short8;  // 8 bf16 = 4 VGPRs
typedef __attribute__((ext_vector_type(4))) float f32x4;   // MFMA C/D frag

__device__ __forceinline__ unsigned short f2bf(float x) {
  __hip_bfloat16 b = __float2bfloat16(x);
  return __builtin_bit_cast(unsigned short, b);
}
__device__ __forceinline__ float bf2f(unsigned short u) {
  return __builtin_bit_cast(float, (unsigned int)u << 16);
}

// Prep: pack AW (fp32) into bf16 MFMA-B-fragment order + extract diagonal.
// Frag idx=(T*16+s)*64+L holds 8 bf16 = AW[T*16+(L&15)][s*32+(L>>4)*8 + j]:
// a wave's B-frag load (lane L reads idx base+L) is 1KB contiguous, L2-hot.
__global__ void pack_b(const float* __restrict__ AW, unsigned short* __restrict__ AWp,
                       float* __restrict__ Adiag) {
  int idx = blockIdx.x * 256 + threadIdx.x;     // 0..32767
  int L = idx & 63, s = (idx >> 6) & 15, T = idx >> 10;
  int n = T * 16 + (L & 15);
  int k = s * 32 + (L >> 4) * 8;
  const float4* src = (const float4*)(AW + n * DZV + k);
  float4 a = src[0], b = src[1];
  union { unsigned short u[8]; short8 v; } p;
  p.u[0] = f2bf(a.x); p.u[1] = f2bf(a.y); p.u[2] = f2bf(a.z); p.u[3] = f2bf(a.w);
  p.u[4] = f2bf(b.x); p.u[5] = f2bf(b.y); p.u[6] = f2bf(b.z); p.u[7] = f2bf(b.w);
  *(short8*)(AWp + idx * 8) = p.v;
  if (idx < DZV) Adiag[idx] = AW[idx * (DZV + 1)];
}

__global__ __launch_bounds__(512, 4) void plrnn_step(
    const float* __restrict__ z, const float* __restrict__ h,
    const unsigned short* __restrict__ AWp, const float* __restrict__ Adiag,
    float* __restrict__ out)
{
  __shared__ unsigned short sA[BM * LDA];  // z_act panel (bf16), 33.3 KB
  __shared__ unsigned short sC[BM * LDA];  // corr = A*min(z,mu)+h (bf16), 33.3 KB

  const int t = threadIdx.x;
  const int row0 = blockIdx.x * BM;

  const int lane = t & 63;
  const int wave = t >> 6;           // 8 waves cover N=512
  const int lr   = lane & 15;
  const int quad = lane >> 4;
  const int nbase = wave * 64;

  // B frag base pointers (packed global, lane-contiguous 1KB per frag-load)
  const unsigned short* bb[4];
  #pragma unroll
  for (int nt = 0; nt < 4; ++nt)
    bb[nt] = AWp + (((wave * 4 + nt) * 16) * 64 + lane) * 8;

  // B pipeline, depth 2 (3 buffers). Issue s=0 and s=1 NOW: these 8 loads
  // fly under phase-1's z loads + reduction + LDS writes + barrier.
  short8 bf[3][4];
  #pragma unroll
  for (int nt = 0; nt < 4; ++nt) {
    bf[0][nt] = *(const short8*)(bb[nt] + 0 * 512);
    bf[1][nt] = *(const short8*)(bb[nt] + 1 * 512);
  }

  // ---- Phase 1: single coalesced pass over z; mean, relu->sA, corr->sC ----
  {
    const int r = t >> 4;          // 0..31, 16 threads per row (consecutive lanes)
    const int c = t & 15;
    const float4* zr = (const float4*)(z + (row0 + r) * DZV);
    float4 v[8];
    float s = 0.f;
    #pragma unroll
    for (int i = 0; i < 8; ++i) {
      v[i] = zr[c + i * 16];                   // coalesced 256B runs
      s += (v[i].x + v[i].y) + (v[i].z + v[i].w);
    }
    s += __shfl_xor(s, 1);
    s += __shfl_xor(s, 2);
    s += __shfl_xor(s, 4);
    s += __shfl_xor(s, 8);
    const float mu = s * (1.0f / 512.0f);
    #pragma unroll
    for (int i = 0; i < 8; ++i) {
      const int c4 = c + i * 16;               // float4 column index
      float4 Ad = ((const float4*)Adiag)[c4];  // L1-hot, 2KB shared
      float4 hv = ((const float4*)h)[c4];
      union { unsigned short u[4]; } pa, pc;
      pa.u[0] = f2bf(fmaxf(v[i].x - mu, 0.f));
      pa.u[1] = f2bf(fmaxf(v[i].y - mu, 0.f));
      pa.u[2] = f2bf(fmaxf(v[i].z - mu, 0.f));
      pa.u[3] = f2bf(fmaxf(v[i].w - mu, 0.f));
      pc.u[0] = f2bf(Ad.x * fminf(v[i].x, mu) + hv.x);
      pc.u[1] = f2bf(Ad.y * fminf(v[i].y, mu) + hv.y);
      pc.u[2] = f2bf(Ad.z * fminf(v[i].z, mu) + hv.z);
      pc.u[3] = f2bf(Ad.w * fminf(v[i].w, mu) + hv.w);
      *(ushort4*)&sA[r * LDA + c4 * 4] = *(ushort4*)pa.u;
      *(ushort4*)&sC[r * LDA + c4 * 4] = *(ushort4*)pc.u;
    }
  }

  __syncthreads();   // only barrier; K-loop below is barrier-free

  // ---- Phase 2: GEMM, 2M x 4N per wave; A double-buffered (LDS),
  //      B triple-buffered (L2, prefetch distance 2). ----
  const unsigned short* a0 = &sA[(lr) * LDA + quad * 8];
  const unsigned short* a1 = &sA[(16 + lr) * LDA + quad * 8];

  short8 af[2][2];
  af[0][0] = *(const short8*)(a0);
  af[0][1] = *(const short8*)(a1);

  f32x4 acc[2][4];
  #pragma unroll
  for (int mt = 0; mt < 2; ++mt)
    #pragma unroll
    for (int nt = 0; nt < 4; ++nt)
      acc[mt][nt] = (f32x4){0.f, 0.f, 0.f, 0.f};

  #pragma unroll
  for (int s = 0; s < 16; ++s) {     // k = s*32
    const int cur = s % 3;           // static after full unroll
    const int anx = (s & 1) ^ 1;
    if (s < 14) {                    // prefetch B for s+2 (L2, dwordx4)
      const int b2 = (s + 2) % 3;
      #pragma unroll
      for (int nt = 0; nt < 4; ++nt)
        bf[b2][nt] = *(const short8*)(bb[nt] + (s + 2) * 512);
    }
    if (s < 15) {                    // prefetch A for s+1 (ds_read_b128)
      af[anx][0] = *(const short8*)(a0 + (s + 1) * 32);
      af[anx][1] = *(const short8*)(a1 + (s + 1) * 32);
    }
    #pragma unroll
    for (int nt = 0; nt < 4; ++nt) {
      acc[0][nt] = __builtin_amdgcn_mfma_f32_16x16x32_bf16(af[s & 1][0], bf[cur][nt], acc[0][nt], 0, 0, 0);
      acc[1][nt] = __builtin_amdgcn_mfma_f32_16x16x32_bf16(af[s & 1][1], bf[cur][nt], acc[1][nt], 0, 0, 0);
    }
  }

  // ---- Epilogue: out = acc + corr; nt innermost -> 4 adjacent 64B segments
  // per row issued back-to-back so L2 merges full lines.
  #pragma unroll
  for (int mt = 0; mt < 2; ++mt) {
    #pragma unroll
    for (int r = 0; r < 4; ++r) {
      const int lm = mt * 16 + quad * 4 + r;   // C/D layout: row = quad*4 + reg
      float corr[4];
      #pragma unroll
      for (int nt = 0; nt < 4; ++nt)
        corr[nt] = bf2f(sC[lm * LDA + nbase + nt * 16 + lr]);
      float* orow = out + (row0 + lm) * DZV + nbase + lr;
      #pragma unroll
      for (int nt = 0; nt < 4; ++nt)
        orow[nt * 16] = acc[mt][nt][r] + corr[nt];
    }
  }
}

extern "C" void kernel_launch(void* const* d_in, const int* in_sizes, int n_in,
                              void* d_out, int out_size, void* d_ws, size_t ws_size,
                              hipStream_t stream) {
  const float* z  = (const float*)d_in[0];
  const float* AW = (const float*)d_in[1];
  const float* h  = (const float*)d_in[2];
  float* out = (float*)d_out;
  unsigned short* AWp = (unsigned short*)d_ws;                     // 512 KB packed bf16
  float* Adiag = (float*)((char*)d_ws + DZV * DZV * sizeof(unsigned short)); // 2 KB

  pack_b<<<128, 256, 0, stream>>>(AW, AWp, Adiag);
  plrnn_step<<<65536 / BM, 512, 0, stream>>>(z, h, AWp, Adiag, out);
}